// Round 10
// baseline (464.778 us; speedup 1.0000x reference)
//
#include <hip/hip_runtime.h>
#include <hip/hip_bf16.h>
#include <math.h>

#define S_LEN 2048
#define D_MODEL 1024
#define N_BATCH 4
#define N_HALF 512

typedef unsigned short u16;
typedef __attribute__((ext_vector_type(8))) short bf16x8;
typedef __attribute__((ext_vector_type(4))) float f32x4;

// ---------- helpers ----------
__device__ inline u16 f2bf(float v) {
  __hip_bfloat16 h = __float2bfloat16(v);   // RNE
  return *reinterpret_cast<u16*>(&h);
}
__device__ inline float bf2f(u16 u) {
  __hip_bfloat16 h = *reinterpret_cast<__hip_bfloat16*>(&u);
  return __bfloat162float(h);
}
// async global->LDS, 16B per lane; LDS dest is wave-uniform base + lane*16
__device__ inline void gl2lds16(const void* g, void* l) {
  __builtin_amdgcn_global_load_lds(
      (const __attribute__((address_space(1))) unsigned int*)g,
      (__attribute__((address_space(3))) unsigned int*)l, 16, 0, 0);
}
// tanh via v_exp_f32; exact at 0, saturates correctly at +/-inf (no NaN)
__device__ inline float fast_tanh(float x) {
  float e = __expf(2.0f * x);
  return 1.0f - 2.0f / (e + 1.0f);
}
// XCD-chunked bijective swizzle (T1/m157): valid when n % 8 == 0.
__device__ inline int xcd_swz(int hw, int n) {
  return (hw & 7) * (n >> 3) + (hw >> 3);
}

// ============================================================
// ROUND-10: (a) 2-D supertiles inside each XCD chunk (4x4 bn x bm, all
// decodes bijective bit-field partitions) so the per-chunk working set
// fits the 4 MB L2 (chaotic: 8 MB -> 4 MB); (b) out3 epilogue writes
// the w2h/w2l split directly (drops W2f + cast_split launch); (c) cast
// + transpose_split + w2_bias folded into ONE prep launch. All pure
// block remapping / launch fusion: bit-identical GEMM math.
// ============================================================

// ---------- prep mega-kernel ----------
// blocks [0,12288): cast x,Wq,Wk,Wp (plain) + Wo (split), float4 granule
// blocks [12288,13312): transpose_split of Wv
// blocks [13312,13376): w2b[d] = sum_j Wo[d][j]*bv[j], 16 rows/block
#define N0_X   (2097152LL)   // TD/4
#define NW_W   (262144LL)    // WSZ/4
__global__ __launch_bounds__(256)
void prep_multi(const float* __restrict__ sx, u16* __restrict__ dx,
                const float* __restrict__ s1, u16* __restrict__ d1,
                const float* __restrict__ s2, u16* __restrict__ d2,
                const float* __restrict__ s3, u16* __restrict__ d3,
                const float* __restrict__ s4, u16* __restrict__ d4h,
                u16* __restrict__ d4l,
                const float* __restrict__ Wv, u16* __restrict__ wvth,
                u16* __restrict__ wvtl,
                const float* __restrict__ Wo, const float* __restrict__ bv,
                float* __restrict__ w2b) {
  __shared__ float tsh[32][33];
  const int bid = blockIdx.x;
  const int tid = threadIdx.x;
  if (bid < 12288) {
    long long i = (long long)bid * 256 + tid;
    if (i < N0_X) {
      float4 v = ((const float4*)sx)[i];
      ushort4 o;
      o.x = f2bf(v.x); o.y = f2bf(v.y); o.z = f2bf(v.z); o.w = f2bf(v.w);
      ((ushort4*)dx)[i] = o;
      return;
    }
    long long k = i - N0_X;
    int w = (int)(k >> 18);
    long long off = k & (NW_W - 1);
    if (w < 3) {
      const float* s = (w == 0) ? s1 : (w == 1) ? s2 : s3;
      u16* d        = (w == 0) ? d1 : (w == 1) ? d2 : d3;
      float4 v = ((const float4*)s)[off];
      ushort4 o;
      o.x = f2bf(v.x); o.y = f2bf(v.y); o.z = f2bf(v.z); o.w = f2bf(v.w);
      ((ushort4*)d)[off] = o;
    } else {
      float4 v = ((const float4*)s4)[off];
      ushort4 oh, ol;
      float f;
      oh.x = f2bf(v.x); f = v.x - bf2f(oh.x); ol.x = f2bf(f);
      oh.y = f2bf(v.y); f = v.y - bf2f(oh.y); ol.y = f2bf(f);
      oh.z = f2bf(v.z); f = v.z - bf2f(oh.z); ol.z = f2bf(f);
      oh.w = f2bf(v.w); f = v.w - bf2f(oh.w); ol.w = f2bf(f);
      ((ushort4*)d4h)[off] = oh;
      ((ushort4*)d4l)[off] = ol;
    }
    return;
  }
  if (bid < 13312) {
    // transpose + split: dst[i][j] = split(Wv[j][i])
    const int b2 = bid - 12288;
    const int bx = (b2 & 31) * 32;
    const int by = (b2 >> 5) * 32;
    const int c = tid & 31;
    const int r0 = (tid >> 5) * 4;
#pragma unroll
    for (int r = 0; r < 4; r++)
      tsh[r0 + r][c] = Wv[(long long)(by + r0 + r) * D_MODEL + bx + c];
    __syncthreads();
#pragma unroll
    for (int r = 0; r < 4; r++) {
      float v = tsh[c][r0 + r];
      long long idx = (long long)(bx + r0 + r) * D_MODEL + by + c;
      u16 h = f2bf(v);
      wvth[idx] = h;
      wvtl[idx] = f2bf(v - bf2f(h));
    }
    return;
  }
  // w2_bias: 64 blocks x 16 rows (wave w -> rows base+w*4..+3)
  const int base = (bid - 13312) * 16;
  const int wave = tid >> 6;
  const int lane = tid & 63;
#pragma unroll
  for (int rr = 0; rr < 4; rr++) {
    const int d = base + wave * 4 + rr;
    float acc = 0.f;
    for (int j = lane; j < D_MODEL; j += 64)
      acc += Wo[(long long)d * D_MODEL + j] * bv[j];
#pragma unroll
    for (int m = 1; m < 64; m <<= 1) acc += __shfl_xor(acc, m);
    if (lane == 0) w2b[d] = acc;
  }
}

// ============================================================
// MERGED: qk_fused (512 blk, T1 + 4x4 supertile) + out3 (blocks 0..63,
// epilogue now writes w2h/w2l split directly). 64 KB shared LDS arena.
// ============================================================
__global__ __launch_bounds__(256, 2)
void qk_out3(const u16* __restrict__ X, const u16* __restrict__ Wq,
             const u16* __restrict__ Wk,
             const float* __restrict__ bq, const float* __restrict__ bk,
             u16* __restrict__ Qo, u16* __restrict__ Ko,
             const u16* __restrict__ Ah3, const u16* __restrict__ Al3,
             const u16* __restrict__ Bh3, const u16* __restrict__ Bl3,
             u16* __restrict__ w2h, u16* __restrict__ w2l) {
  __shared__ __align__(16) u16 smem[4 * 128 * 64];   // 64 KB
  const int id   = blockIdx.x;
  const int tid  = threadIdx.x;
  const int wave = tid >> 6;
  const int lane = tid & 63;
  const int quad = lane >> 4;
  const int tc   = lane & 15;
  const int wm = (wave & 1) * 64;
  const int wn = (wave >> 1) * 64;
  const int srow8 = lane >> 3;
  const int scol  = ((lane & 7) ^ srow8) * 8;
  const int srowb = wave * 32;
  const int wb = srowb * 64;
  const long long r8 = 8LL * D_MODEL;
  const int swzA = tc & 7;

  if (id < 64) {
    // ---------------- out3 body: split(W2) = (Ah+Al)(Bh+Bl)^T ----------
    u16* Ash = smem;
    u16* Asl = smem + 8192;
    u16* Bsh = smem + 16384;
    u16* Bsl = smem + 24576;
    const int bm = (id >> 3) * 128;
    const int bn = (id & 7) * 128;

    f32x4 acc[4][4];
#pragma unroll
    for (int i = 0; i < 4; i++)
#pragma unroll
      for (int j = 0; j < 4; j++) acc[i][j] = (f32x4){0.f, 0.f, 0.f, 0.f};

    long long aoff = (long long)(bm + srowb + srow8) * D_MODEL + scol;
    long long boff = (long long)(bn + srowb + srow8) * D_MODEL + scol;
    const u16 *gah = Ah3 + aoff, *gal = Al3 + aoff;
    const u16 *gbh = Bh3 + boff, *gbl = Bl3 + boff;

    for (int k0 = 0; k0 < D_MODEL; k0 += 64) {
#pragma unroll
      for (int c = 0; c < 4; c++) {
        gl2lds16(gah + c * r8, Ash + wb + c * 512);
        gl2lds16(gal + c * r8, Asl + wb + c * 512);
        gl2lds16(gbh + c * r8, Bsh + wb + c * 512);
        gl2lds16(gbl + c * r8, Bsl + wb + c * 512);
      }
      gah += 64; gal += 64; gbh += 64; gbl += 64;
      __syncthreads();
      bf16x8 ah[4][2], al[4][2], bh[4][2], bl[4][2];
#pragma unroll
      for (int i = 0; i < 4; i++) {
        const int ra = (wm + i * 16 + tc) * 64;
        const int rb = (wn + i * 16 + tc) * 64;
#pragma unroll
        for (int ks = 0; ks < 2; ks++) {
          const int co = ((ks * 4 + quad) ^ swzA) * 8;
          ah[i][ks] = *(const bf16x8*)(Ash + ra + co);
          al[i][ks] = *(const bf16x8*)(Asl + ra + co);
          bh[i][ks] = *(const bf16x8*)(Bsh + rb + co);
          bl[i][ks] = *(const bf16x8*)(Bsl + rb + co);
        }
      }
#pragma unroll
      for (int i = 0; i < 4; i++)
#pragma unroll
        for (int j = 0; j < 4; j++) {
#pragma unroll
          for (int ks = 0; ks < 2; ks++) {
            acc[i][j] = __builtin_amdgcn_mfma_f32_16x16x32_bf16(ah[i][ks], bh[j][ks], acc[i][j], 0, 0, 0);
            acc[i][j] = __builtin_amdgcn_mfma_f32_16x16x32_bf16(ah[i][ks], bl[j][ks], acc[i][j], 0, 0, 0);
            acc[i][j] = __builtin_amdgcn_mfma_f32_16x16x32_bf16(al[i][ks], bh[j][ks], acc[i][j], 0, 0, 0);
          }
        }
      __syncthreads();
    }
#pragma unroll
    for (int i = 0; i < 4; i++) {
      const int row0 = bm + wm + i * 16 + quad * 4;
#pragma unroll
      for (int j = 0; j < 4; j++) {
        const int col = bn + wn + j * 16 + tc;
#pragma unroll
        for (int r = 0; r < 4; r++) {
          long long idx = (long long)(row0 + r) * D_MODEL + col;
          float v = acc[i][j][r];
          u16 h = f2bf(v);
          w2h[idx] = h;
          w2l[idx] = f2bf(v - bf2f(h));
        }
      }
    }
  } else {
    // ------------- qk body: T1 + 4x4 supertile decode -------------
    u16* Xs = smem;
    u16* Qs = smem + 8192;
    u16* Ks = smem + 16384;
    const int qs = xcd_swz(id - 64, 512);
    const int chunk = qs >> 6;
    const int t = qs & 63;
    const int st = t >> 4, sp = t & 15;
    const int bn = (((st & 1) << 2) + (sp & 3)) * 128;
    const int bm = (chunk * 8 + ((st >> 1) << 2) + (sp >> 2)) * 128;

    f32x4 acc1[4][4], acc2[4][4];
#pragma unroll
    for (int i = 0; i < 4; i++)
#pragma unroll
      for (int j = 0; j < 4; j++) {
        acc1[i][j] = (f32x4){0.f, 0.f, 0.f, 0.f};
        acc2[i][j] = (f32x4){0.f, 0.f, 0.f, 0.f};
      }

    const u16* gx = X  + (long long)(bm + srowb + srow8) * D_MODEL + scol;
    const u16* gq = Wq + (long long)(bn + srowb + srow8) * D_MODEL + scol;
    const u16* gk = Wk + (long long)(bn + srowb + srow8) * D_MODEL + scol;

    for (int k0 = 0; k0 < D_MODEL; k0 += 64) {
#pragma unroll
      for (int c = 0; c < 4; c++) {
        gl2lds16(gx + c * r8, Xs + wb + c * 512);
        gl2lds16(gq + c * r8, Qs + wb + c * 512);
        gl2lds16(gk + c * r8, Ks + wb + c * 512);
      }
      gx += 64; gq += 64; gk += 64;
      __syncthreads();
      bf16x8 af[4][2], bq4[4][2], bk4[4][2];
#pragma unroll
      for (int i = 0; i < 4; i++) {
        const int ra = (wm + i * 16 + tc) * 64;
        const int rb = (wn + i * 16 + tc) * 64;
#pragma unroll
        for (int ks = 0; ks < 2; ks++) {
          const int co = ((ks * 4 + quad) ^ swzA) * 8;
          af[i][ks]  = *(const bf16x8*)(Xs + ra + co);
          bq4[i][ks] = *(const bf16x8*)(Qs + rb + co);
          bk4[i][ks] = *(const bf16x8*)(Ks + rb + co);
        }
      }
#pragma unroll
      for (int i = 0; i < 4; i++)
#pragma unroll
        for (int j = 0; j < 4; j++) {
          acc1[i][j] = __builtin_amdgcn_mfma_f32_16x16x32_bf16(af[i][0], bq4[j][0], acc1[i][j], 0, 0, 0);
          acc2[i][j] = __builtin_amdgcn_mfma_f32_16x16x32_bf16(af[i][0], bk4[j][0], acc2[i][j], 0, 0, 0);
          acc1[i][j] = __builtin_amdgcn_mfma_f32_16x16x32_bf16(af[i][1], bq4[j][1], acc1[i][j], 0, 0, 0);
          acc2[i][j] = __builtin_amdgcn_mfma_f32_16x16x32_bf16(af[i][1], bk4[j][1], acc2[i][j], 0, 0, 0);
        }
      __syncthreads();
    }

#pragma unroll
    for (int i = 0; i < 4; i++) {
      const int row0 = bm + wm + i * 16 + quad * 4;
#pragma unroll
      for (int j = 0; j < 4; j++) {
        const int col = bn + wn + j * 16 + tc;
#pragma unroll
        for (int r = 0; r < 4; r++) {
          long long idx = (long long)(row0 + r) * D_MODEL + col;
          Qo[idx] = f2bf(acc1[i][j][r] + bq[col]);
          Ko[idx] = f2bf(acc2[i][j][r] + bk[col]);
        }
      }
    }
  }
}

// ============================================================
// Fused pfQ+pfK projection + in-kernel phase normalize.
// T1 + 4x4 supertile decode.
// ============================================================
__global__ __launch_bounds__(256, 2)
void pf_fused(const u16* __restrict__ Qb, const u16* __restrict__ Wp,
              const float* __restrict__ bp,
              u16* __restrict__ pfQ, u16* __restrict__ pfK,
              long long TDo) {
  __shared__ u16 lds_all[3 * 128 * 64];   // Qs | Ks | Ws (48 KB)
  u16* Qs = lds_all;
  u16* Ks = lds_all + 128 * 64;
  u16* Ws = lds_all + 2 * 128 * 64;
  const int tid  = threadIdx.x;
  const int wave = tid >> 6;
  const int lane = tid & 63;
  const int quad = lane >> 4;
  const int tc   = lane & 15;
  const int oid = xcd_swz(blockIdx.x, 512);
  const int chunk = oid >> 6;
  const int t = oid & 63;
  const int st = t >> 4, sp = t & 15;
  const int bn = (((st & 1) << 2) + (sp & 3)) * 64;   // re-col base (im = +512)
  const int bm = (chunk * 8 + ((st >> 1) << 2) + (sp >> 2)) * 128;
  const int wm = (wave & 1) * 64;
  const int grp = wave >> 1;               // 0: re-group, 1: im-group

  f32x4 acc1[4][4], acc2[4][4];
#pragma unroll
  for (int i = 0; i < 4; i++)
#pragma unroll
    for (int j = 0; j < 4; j++) {
      acc1[i][j] = (f32x4){0.f, 0.f, 0.f, 0.f};
      acc2[i][j] = (f32x4){0.f, 0.f, 0.f, 0.f};
    }

  const int srow8 = lane >> 3;
  const int scol  = ((lane & 7) ^ srow8) * 8;
  const int srowb = wave * 32;
  const u16* gq = Qb + (long long)(bm + srowb + srow8) * D_MODEL + scol;
  const u16* gk = gq + TDo;
  const u16* gw = Wp + (long long)(bn + srowb + srow8 + ((wave & 2) ? 448 : 0)) * D_MODEL + scol;
  const int wb = srowb * 64;
  const long long r8 = 8LL * D_MODEL;
  const int swzA = tc & 7;

  for (int k0 = 0; k0 < D_MODEL; k0 += 64) {
#pragma unroll
    for (int c = 0; c < 4; c++) {
      gl2lds16(gq + c * r8, Qs + wb + c * 512);
      gl2lds16(gk + c * r8, Ks + wb + c * 512);
      gl2lds16(gw + c * r8, Ws + wb + c * 512);
    }
    gq += 64; gk += 64; gw += 64;
    __syncthreads();
    bf16x8 aq[4][2], ak[4][2], bw[4][2];
    const int wn = grp * 64;
#pragma unroll
    for (int i = 0; i < 4; i++) {
      const int ra = (wm + i * 16 + tc) * 64;
      const int rb = (wn + i * 16 + tc) * 64;
#pragma unroll
      for (int ks = 0; ks < 2; ks++) {
        const int co = ((ks * 4 + quad) ^ swzA) * 8;
        aq[i][ks] = *(const bf16x8*)(Qs + ra + co);
        ak[i][ks] = *(const bf16x8*)(Ks + ra + co);
        bw[i][ks] = *(const bf16x8*)(Ws + rb + co);
      }
    }
#pragma unroll
    for (int i = 0; i < 4; i++)
#pragma unroll
      for (int j = 0; j < 4; j++) {
        acc1[i][j] = __builtin_amdgcn_mfma_f32_16x16x32_bf16(aq[i][0], bw[j][0], acc1[i][j], 0, 0, 0);
        acc2[i][j] = __builtin_amdgcn_mfma_f32_16x16x32_bf16(ak[i][0], bw[j][0], acc2[i][j], 0, 0, 0);
        acc1[i][j] = __builtin_amdgcn_mfma_f32_16x16x32_bf16(aq[i][1], bw[j][1], acc1[i][j], 0, 0, 0);
        acc2[i][j] = __builtin_amdgcn_mfma_f32_16x16x32_bf16(ak[i][1], bw[j][1], acc2[i][j], 0, 0, 0);
      }
    __syncthreads();
  }

  // ---- fused phase-normalize epilogue (exchange via LDS, 4 rounds) ----
  float* ex = (float*)lds_all;             // 32 KB of the 48 KB staging
  const long long colbase = (long long)bn + (long long)grp * 512;
#pragma unroll
  for (int o = 0; o < 2; o++) {
    u16* Ou = o ? pfK : pfQ;
#pragma unroll
    for (int half = 0; half < 2; half++) {
      int cnt = 0;
#pragma unroll
      for (int i = 2 * half; i < 2 * half + 2; i++)
#pragma unroll
        for (int j = 0; j < 4; j++) {
          f32x4 v = o ? acc2[i][j] : acc1[i][j];
          float b = bp[colbase + j * 16 + tc];
          v[0] += b; v[1] += b; v[2] += b; v[3] += b;
          *(f32x4*)(ex + wave * 2048 + cnt * 256 + lane * 4) = v;
          cnt++;
        }
      __syncthreads();
      cnt = 0;
#pragma unroll
      for (int i = 2 * half; i < 2 * half + 2; i++)
#pragma unroll
        for (int j = 0; j < 4; j++) {
          f32x4 own = *(const f32x4*)(ex + wave * 2048 + cnt * 256 + lane * 4);
          f32x4 oth = *(const f32x4*)(ex + (wave ^ 2) * 2048 + cnt * 256 + lane * 4);
          const int row0 = bm + wm + i * 16 + quad * 4;
          const long long col = colbase + j * 16 + tc;
#pragma unroll
          for (int r = 0; r < 4; r++) {
            float a = own[r], p = oth[r];
            float n2 = a * a + p * p;
            float outv = (grp == 0) ? 1.f : 0.f;
            if (n2 > 0.f) outv = a * (1.0f / sqrtf(n2));
            Ou[(long long)(row0 + r) * D_MODEL + col] = f2bf(outv);
          }
          cnt++;
        }
      __syncthreads();
    }
  }
}

// ============================================================
// MERGED: chaotic_fused + vwt_kernel, interleaved 2:1, T1 + supertiles.
// chaotic: 4x4 (bn x bm) supertiles within each 128-cid chunk;
// vwt: 4x4 within each 64-vid chunk. Bodies = validated BK=64 swizzled.
// ============================================================
__global__ __launch_bounds__(256, 2)
void chaotic_vwt(const u16* __restrict__ Q, const u16* __restrict__ Kt,
                 const u16* __restrict__ Uq, const u16* __restrict__ Uk,
                 float* __restrict__ Cc,
                 float* __restrict__ ssum, float* __restrict__ ssq,
                 const float* __restrict__ bifp, const float* __restrict__ pcp,
                 const u16* __restrict__ W2h, const u16* __restrict__ W2l,
                 const u16* __restrict__ X, const float* __restrict__ w2b,
                 u16* __restrict__ Ch, u16* __restrict__ Cl,
                 long long sB, long long sC,
                 int interleave, int nchao) {
  __shared__ __align__(16) u16 smem[4 * 128 * 64];   // 64 KB
  const int id = xcd_swz(blockIdx.x, (int)gridDim.x);   // T1 (grid % 8 == 0)
  int cid = -1, vid = -1;
  if (interleave) {
    if ((id % 3) == 2) vid = id / 3;
    else cid = (id / 3) * 2 + (id % 3);
  } else {
    if (id < nchao) cid = id; else vid = id - nchao;
  }

  const int tid  = threadIdx.x;
  const int wave = tid >> 6;
  const int lane = tid & 63;
  const int quad = lane >> 4;
  const int tc   = lane & 15;
  const int wm = (wave & 1) * 64;
  const int wn = (wave >> 1) * 64;
  const int srow8 = lane >> 3;
  const int scol  = ((lane & 7) ^ srow8) * 8;
  const int srowb = wave * 32;
  const int wb = srowb * 64;
  const long long r8 = 8LL * D_MODEL;
  const int swzA = tc & 7;

  if (cid >= 0) {
    // ---------------- chaotic body (4x4 supertile decode) ----------------
    u16* Qs = smem;
    u16* Ks = smem + 8192;
    u16* Us = smem + 16384;
    u16* Ws = smem + 24576;
    const int chunk = cid >> 7;
    const int t = cid & 127;
    const int st = t >> 4, sp = t & 15;
    const int bn = (((st & 3) << 2) + (sp & 3)) * 128;
    const int bm = (((chunk & 1) << 3) + ((st >> 2) << 2) + (sp >> 2)) * 128;
    const long long z = chunk >> 1;
    const long long sQ = (long long)S_LEN * D_MODEL;

    f32x4 acc1[4][4], acc2[4][4];
#pragma unroll
    for (int i = 0; i < 4; i++)
#pragma unroll
      for (int j = 0; j < 4; j++) {
        acc1[i][j] = (f32x4){0.f, 0.f, 0.f, 0.f};
        acc2[i][j] = (f32x4){0.f, 0.f, 0.f, 0.f};
      }

    const u16* gq = Q  + z * sQ + (long long)(bm + srowb + srow8) * D_MODEL + scol;
    const u16* gk = Kt + z * sQ + (long long)(bn + srowb + srow8) * D_MODEL + scol;
    const u16* gu = Uq + z * sQ + (long long)(bm + srowb + srow8) * D_MODEL + scol;
    const u16* gw = Uk + z * sQ + (long long)(bn + srowb + srow8) * D_MODEL + scol;

    for (int k0 = 0; k0 < D_MODEL; k0 += 64) {
#pragma unroll
      for (int c = 0; c < 4; c++) {
        gl2lds16(gq + c * r8, Qs + wb + c * 512);
        gl2lds16(gk + c * r8, Ks + wb + c * 512);
        gl2lds16(gu + c * r8, Us + wb + c * 512);
        gl2lds16(gw + c * r8, Ws + wb + c * 512);
      }
      gq += 64; gk += 64; gu += 64; gw += 64;
      __syncthreads();
      {   // GEMM 1: scores = Q @ K^T
        bf16x8 af[4][2], bg[4][2];
#pragma unroll
        for (int i = 0; i < 4; i++) {
          const int ra = (wm + i * 16 + tc) * 64;
          const int rb = (wn + i * 16 + tc) * 64;
#pragma unroll
          for (int ks = 0; ks < 2; ks++) {
            const int co = ((ks * 4 + quad) ^ swzA) * 8;
            af[i][ks] = *(const bf16x8*)(Qs + ra + co);
            bg[i][ks] = *(const bf16x8*)(Ks + rb + co);
          }
        }
#pragma unroll
        for (int i = 0; i < 4; i++)
#pragma unroll
          for (int j = 0; j < 4; j++) {
            acc1[i][j] = __builtin_amdgcn_mfma_f32_16x16x32_bf16(af[i][0], bg[j][0], acc1[i][j], 0, 0, 0);
            acc1[i][j] = __builtin_amdgcn_mfma_f32_16x16x32_bf16(af[i][1], bg[j][1], acc1[i][j], 0, 0, 0);
          }
      }
      {   // GEMM 2: sync = Uq @ Uk^T
        bf16x8 cf[4][2], dg[4][2];
#pragma unroll
        for (int i = 0; i < 4; i++) {
          const int ra = (wm + i * 16 + tc) * 64;
          const int rb = (wn + i * 16 + tc) * 64;
#pragma unroll
          for (int ks = 0; ks < 2; ks++) {
            const int co = ((ks * 4 + quad) ^ swzA) * 8;
            cf[i][ks] = *(const bf16x8*)(Us + ra + co);
            dg[i][ks] = *(const bf16x8*)(Ws + rb + co);
          }
        }
#pragma unroll
        for (int i = 0; i < 4; i++)
#pragma unroll
          for (int j = 0; j < 4; j++) {
            acc2[i][j] = __builtin_amdgcn_mfma_f32_16x16x32_bf16(cf[i][0], dg[j][0], acc2[i][j], 0, 0, 0);
            acc2[i][j] = __builtin_amdgcn_mfma_f32_16x16x32_bf16(cf[i][1], dg[j][1], acc2[i][j], 0, 0, 0);
          }
      }
      __syncthreads();
    }

    const float bif = *bifp;
    const float pc  = *pcp;
    float rsum[4][4], rsq[4][4];
#pragma unroll
    for (int i = 0; i < 4; i++)
#pragma unroll
      for (int r = 0; r < 4; r++) { rsum[i][r] = 0.f; rsq[i][r] = 0.f; }

    float* C = Cc + z * (long long)S_LEN * S_LEN;
#pragma unroll
    for (int i = 0; i < 4; i++) {
      const int row0 = bm + wm + i * 16 + quad * 4;
#pragma unroll
      for (int j = 0; j < 4; j++) {
        const int col = bn + wn + j * 16 + tc;
#pragma unroll
        for (int r = 0; r < 4; r++) {
          float sc = acc1[i][j][r] * 0.03125f;          // / sqrt(1024)
          float sy = acc2[i][j][r] * (1.0f / 512.0f);   // / HALF
          float t2 = fast_tanh(sc);
          C[(long long)(row0 + r) * S_LEN + col] = sc + pc * sy + bif * t2 * (1.0f - t2);
          rsum[i][r] += sy;
          rsq[i][r]  += sy * sy;
        }
      }
    }
#pragma unroll
    for (int m = 1; m < 16; m <<= 1) {
#pragma unroll
      for (int i = 0; i < 4; i++)
#pragma unroll
        for (int r = 0; r < 4; r++) {
          rsum[i][r] += __shfl_xor(rsum[i][r], m);
          rsq[i][r]  += __shfl_xor(rsq[i][r], m);
        }
    }
    if (tc == 0) {
#pragma unroll
      for (int i = 0; i < 4; i++)
#pragma unroll
        for (int r = 0; r < 4; r++) {
          long long rr = z * S_LEN + bm + wm + i * 16 + quad * 4 + r;
          atomicAdd(&ssum[rr], rsum[i][r]);
          atomicAdd(&ssq[rr],  rsq[i][r]);
        }
    }
  } else {
    // ---------------- vwt body (4x4 supertile decode) ----------------
    u16* Ah = smem;
    u16* Al = smem + 8192;
    u16* Bs = smem + 16384;
    const int chunk = vid >> 6;
    const int t = vid & 63;
    const int bn = (((t >> 4) << 2) + (t & 3)) * 128;          // s
    const int bm = (((chunk & 1) << 2) + ((t >> 2) & 3)) * 128; // d
    const long long z = chunk >> 1;

    f32x4 acc[4][4];
#pragma unroll
    for (int i = 0; i < 4; i++)
#pragma unroll
      for (int j = 0; j < 4; j++) acc[i][j] = (f32x4){0.f, 0.f, 0.f, 0.f};

    const long long aoff = (long long)(bm + srowb + srow8) * D_MODEL + scol;
    const u16* gah = W2h + aoff;
    const u16* gal = W2l + aoff;
    const u16* gb  = X + z * sB + (long long)(bn + srowb + srow8) * D_MODEL + scol;

    for (int k0 = 0; k0 < D_MODEL; k0 += 64) {
#pragma unroll
      for (int c = 0; c < 4; c++) {
        gl2lds16(gah + c * r8, Ah + wb + c * 512);
        gl2lds16(gal + c * r8, Al + wb + c * 512);
        gl2lds16(gb  + c * r8, Bs + wb + c * 512);
      }
      gah += 64; gal += 64; gb += 64;
      __syncthreads();
      bf16x8 ah4[4][2], al4[4][2], bx[4][2];
#pragma unroll
      for (int i = 0; i < 4; i++) {
        const int ra = (wm + i * 16 + tc) * 64;
        const int rb = (wn + i * 16 + tc) * 64;
#pragma unroll
        for (int ks = 0; ks < 2; ks++) {
          const int co = ((ks * 4 + quad) ^ swzA) * 8;
          ah4[i][ks] = *(const bf16x8*)(Ah + ra + co);
          al4[i][ks] = *(const bf16x8*)(Al + ra + co);
          bx[i][ks]  = *(const bf16x8*)(Bs + rb + co);
        }
      }
#pragma unroll
      for (int i = 0; i < 4; i++)
#pragma unroll
        for (int j = 0; j < 4; j++) {
          acc[i][j] = __builtin_amdgcn_mfma_f32_16x16x32_bf16(ah4[i][0], bx[j][0], acc[i][j], 0, 0, 0);
          acc[i][j] = __builtin_amdgcn_mfma_f32_16x16x32_bf16(al4[i][0], bx[j][0], acc[i][j], 0, 0, 0);
          acc[i][j] = __builtin_amdgcn_mfma_f32_16x16x32_bf16(ah4[i][1], bx[j][1], acc[i][j], 0, 0, 0);
          acc[i][j] = __builtin_amdgcn_mfma_f32_16x16x32_bf16(al4[i][1], bx[j][1], acc[i][j], 0, 0, 0);
        }
      __syncthreads();
    }

    u16* Chz = Ch + z * sC;
    u16* Clz = Cl + z * sC;
#pragma unroll
    for (int i = 0; i < 4; i++) {
      const int row0 = bm + wm + i * 16 + quad * 4;
#pragma unroll
      for (int j = 0; j < 4; j++) {
        const int col = bn + wn + j * 16 + tc;
#pragma unroll
        for (int r = 0; r < 4; r++) {
          float v = acc[i][j][r] + w2b[row0 + r];
          long long idx = (long long)(row0 + r) * S_LEN + col;
          u16 h = f2bf(v);
          Chz[idx] = h;
          Clz[idx] = f2bf(v - bf2f(h));
        }
      }
    }
  }
}

// ============================================================
// B-split GEMM (out): C = A @ (Bh+Bl)^T + bias[col], fp32 out.
// T1 + 2x4 supertile decode (2 bn x 4 bm = 4 MB working set).
// ============================================================
__global__ __launch_bounds__(256)
void gemm_bsplit(const u16* __restrict__ A,
                 const u16* __restrict__ Bh, const u16* __restrict__ Bl,
                 const float* __restrict__ bias, float* __restrict__ C,
                 int N, int K, long long sA, long long sB, long long sC) {
  __shared__ u16 As[128 * 64];
  __shared__ u16 Bsh[128 * 64];
  __shared__ u16 Bsl[128 * 64];
  const int tid  = threadIdx.x;
  const int wave = tid >> 6;
  const int lane = tid & 63;
  const int quad = lane >> 4;
  const int tc   = lane & 15;
  const int oid = xcd_swz(blockIdx.x, (int)gridDim.x);   // T1
  const int chunk = oid >> 6;
  const int t = oid & 63;
  const int st = t >> 3, sp = t & 7;
  const int bn = ((((st & 3) << 1) + (sp & 1))) * 128;
  const int bm = ((((chunk & 1) << 3) + ((st >> 2) << 2) + (sp >> 1))) * 128;
  const long long z = chunk >> 1;
  const int wm = (wave & 1) * 64;
  const int wn = (wave >> 1) * 64;

  f32x4 acc[4][4];
#pragma unroll
  for (int i = 0; i < 4; i++)
#pragma unroll
    for (int j = 0; j < 4; j++) acc[i][j] = (f32x4){0.f, 0.f, 0.f, 0.f};

  const int srow8 = lane >> 3;
  const int scol  = ((lane & 7) ^ srow8) * 8;
  const int srowb = wave * 32;
  const long long boff = (long long)(bn + srowb + srow8) * K + scol;
  const u16* ga  = A + z * sA + (long long)(bm + srowb + srow8) * K + scol;
  const u16* gbh = Bh + z * sB + boff;
  const u16* gbl = Bl + z * sB + boff;
  const int wb = srowb * 64;
  const long long r8K = 8LL * K;
  const int swzA = tc & 7;

  for (int k0 = 0; k0 < K; k0 += 64) {
#pragma unroll
    for (int c = 0; c < 4; c++) {
      gl2lds16(ga  + c * r8K, As  + wb + c * 512);
      gl2lds16(gbh + c * r8K, Bsh + wb + c * 512);
      gl2lds16(gbl + c * r8K, Bsl + wb + c * 512);
    }
    ga += 64; gbh += 64; gbl += 64;
    __syncthreads();
    bf16x8 af[4][2], bh[4][2], bl[4][2];
#pragma unroll
    for (int i = 0; i < 4; i++) {
      const int ra = (wm + i * 16 + tc) * 64;
      const int rb = (wn + i * 16 + tc) * 64;
#pragma unroll
      for (int ks = 0; ks < 2; ks++) {
        const int co = ((ks * 4 + quad) ^ swzA) * 8;
        af[i][ks] = *(const bf16x8*)(As  + ra + co);
        bh[i][ks] = *(const bf16x8*)(Bsh + rb + co);
        bl[i][ks] = *(const bf16x8*)(Bsl + rb + co);
      }
    }
#pragma unroll
    for (int i = 0; i < 4; i++)
#pragma unroll
      for (int j = 0; j < 4; j++) {
        acc[i][j] = __builtin_amdgcn_mfma_f32_16x16x32_bf16(af[i][0], bh[j][0], acc[i][j], 0, 0, 0);
        acc[i][j] = __builtin_amdgcn_mfma_f32_16x16x32_bf16(af[i][0], bl[j][0], acc[i][j], 0, 0, 0);
        acc[i][j] = __builtin_amdgcn_mfma_f32_16x16x32_bf16(af[i][1], bh[j][1], acc[i][j], 0, 0, 0);
        acc[i][j] = __builtin_amdgcn_mfma_f32_16x16x32_bf16(af[i][1], bl[j][1], acc[i][j], 0, 0, 0);
      }
    __syncthreads();
  }

  float* Cz = C + z * sC;
#pragma unroll
  for (int i = 0; i < 4; i++) {
    const int row0 = bm + wm + i * 16 + quad * 4;
#pragma unroll
    for (int j = 0; j < 4; j++) {
      const int col = bn + wn + j * 16 + tc;
#pragma unroll
      for (int r = 0; r < 4; r++)
        Cz[(long long)(row0 + r) * N + col] = acc[i][j][r] + bias[col];
    }
  }
}

// ============================================================
// Row softmax: fp32 in (chaotic), bf16 out (attn). 1 block / row.
// Vectorized: 2x float4 loads + 2x ushort4 stores per lane.
// ============================================================
__global__ __launch_bounds__(256)
void softmax_bf(const float* __restrict__ Cc, u16* __restrict__ P) {
  const long long row = (long long)blockIdx.y * S_LEN + blockIdx.x;
  const int tid = threadIdx.x;
  const float* p = Cc + row * S_LEN + tid * 8;
  u16* q = P + row * S_LEN + tid * 8;
  float4 a = *(const float4*)p;
  float4 b = *(const float4*)(p + 4);
  float v[8] = {a.x, a.y, a.z, a.w, b.x, b.y, b.z, b.w};
  float m = v[0];
#pragma unroll
  for (int i = 1; i < 8; i++) m = fmaxf(m, v[i]);
#pragma unroll
  for (int mask = 1; mask < 64; mask <<= 1) m = fmaxf(m, __shfl_xor(m, mask));
  __shared__ float red[8];
  if ((tid & 63) == 0) red[tid >> 6] = m;
  __syncthreads();
  m = fmaxf(fmaxf(red[0], red[1]), fmaxf(red[2], red[3]));
  float s = 0.f;
#pragma unroll
  for (int i = 0; i < 8; i++) { v[i] = __expf(v[i] - m); s += v[i]; }
#pragma unroll
  for (int mask = 1; mask < 64; mask <<= 1) s += __shfl_xor(s, mask);
  __syncthreads();
  if ((tid & 63) == 0) red[4 + (tid >> 6)] = s;
  __syncthreads();
  s = red[4] + red[5] + red[6] + red[7];
  float inv = 1.0f / s;
  ushort4 o0, o1;
  o0.x = f2bf(v[0] * inv); o0.y = f2bf(v[1] * inv);
  o0.z = f2bf(v[2] * inv); o0.w = f2bf(v[3] * inv);
  o1.x = f2bf(v[4] * inv); o1.y = f2bf(v[5] * inv);
  o1.z = f2bf(v[6] * inv); o1.w = f2bf(v[7] * inv);
  *(ushort4*)q = o0;
  *(ushort4*)(q + 4) = o1;
}

// ============================================================
// sync_loss
// ============================================================
__global__ __launch_bounds__(1024)
void syncloss_kernel(const float* __restrict__ ssum, const float* __restrict__ ssq,
                     float* __restrict__ out) {
  const int tid = threadIdx.x;
  float acc = 0.f;
  for (int r = tid; r < N_BATCH * S_LEN; r += 1024) {
    float su = ssum[r], sq = ssq[r];
    acc += (sq - su * su * (1.0f / 2048.0f)) * (1.0f / 2047.0f);
  }
#pragma unroll
  for (int mask = 1; mask < 64; mask <<= 1) acc += __shfl_xor(acc, mask);
  __shared__ float red[16];
  if ((tid & 63) == 0) red[tid >> 6] = acc;
  __syncthreads();
  if (tid == 0) {
    float t = 0.f;
#pragma unroll
    for (int k = 0; k < 16; k++) t += red[k];
    out[0] = 0.01f * (t / (float)(N_BATCH * S_LEN));
  }
}

extern "C" void kernel_launch(void* const* d_in, const int* in_sizes, int n_in,
                              void* d_out, int out_size, void* d_ws, size_t ws_size,
                              hipStream_t stream) {
  const float* x    = (const float*)d_in[0];
  const float* Wq   = (const float*)d_in[1];
  const float* bq   = (const float*)d_in[2];
  const float* Wk   = (const float*)d_in[3];
  const float* bk   = (const float*)d_in[4];
  const float* Wv   = (const float*)d_in[5];
  const float* bv   = (const float*)d_in[6];
  const float* Wp   = (const float*)d_in[7];
  const float* bp   = (const float*)d_in[8];
  const float* Wo   = (const float*)d_in[9];
  const float* bo   = (const float*)d_in[10];
  const float* bifp = (const float*)d_in[11];
  const float* pcp  = (const float*)d_in[12];
  float* out = (float*)d_out;

  const long long NROW = (long long)N_BATCH * S_LEN;   // 8192
  const long long TD   = NROW * D_MODEL;               // 8,388,608
  const long long WSZ  = (long long)D_MODEL * D_MODEL; // 1,048,576

  // workspace layout (unchanged; W2f slot now unused)
  u16* xbf   = (u16*)d_ws;          // TD
  u16* wqb   = xbf + TD;            // WSZ
  u16* wkb   = wqb + WSZ;           // WSZ
  u16* wpb   = wkb + WSZ;           // WSZ
  u16* woh   = wpb + WSZ;           // WSZ (Wo hi/lo)
  u16* wol   = woh + WSZ;
  u16* wvth  = wol + WSZ;           // WSZ (Wv^T hi/lo)
  u16* wvtl  = wvth + WSZ;
  u16* w2h   = wvtl + WSZ;          // WSZ (W2 hi/lo)
  u16* w2l   = w2h + WSZ;
  float* W2f = (float*)(w2l + WSZ); // WSZ floats (unused slot, kept for layout)
  float* w2b = W2f + WSZ;           // 1024 floats
  u16* Qbf   = (u16*)(w2b + D_MODEL); // TD
  u16* Kbf   = Qbf + TD;            // TD (contiguous)
  u16* pfQ   = Kbf + TD;            // TD
  u16* pfK   = pfQ + TD;            // TD (contiguous)
  float* Cc  = (float*)(pfK + TD);  // B*S*S fp32 (67 MB)
  float* ssum = Cc + (long long)N_BATCH * S_LEN * S_LEN;
  float* ssq  = ssum + NROW;
  u16* attn = Qbf;                  // overlays Q+K after chaotic (2*TD)
  u16* vwh  = pfQ;                  // fallback overlay (Uq dead after chaotic)
  u16* vwl  = pfK;
  // fresh vwt buffers for the fused path
  u16* vwh2 = (u16*)(ssq + NROW);
  u16* vwl2 = vwh2 + TD;
  const size_t need = (size_t)((char*)(vwl2 + TD) - (char*)d_ws);
  const bool fused = (ws_size >= need);

  dim3 blk(256);
  const long long sQ = (long long)S_LEN * D_MODEL;   // 2048*1024
  const long long sS = (long long)S_LEN * S_LEN;

  // ---- prep: casts + Wv transpose-split + w2_bias in ONE launch ----
  prep_multi<<<13376, blk, 0, stream>>>(x, xbf, Wq, wqb, Wk, wkb, Wp, wpb,
                                        Wo, woh, wol, Wv, wvth, wvtl,
                                        Wo, bv, w2b);
  // ---- merged: Q,K projection (T1+supertile) + W2 GEMM->split ----
  qk_out3<<<576, blk, 0, stream>>>(xbf, wqb, wkb, bq, bk, Qbf, Kbf,
                                   woh, wol, wvth, wvtl, w2h, w2l);

  // ---- pfQ,pfK fused projection + phase normalize (T1+supertile) ----
  pf_fused<<<512, blk, 0, stream>>>(Qbf, wpb, bp, pfQ, pfK, TD);
  hipMemsetAsync(ssum, 0, (size_t)(2 * NROW) * sizeof(float), stream);

  // ---- merged chaotic + vwt (2:1, T1+supertile) or sequential fallback ----
  if (fused) {
    chaotic_vwt<<<1536, blk, 0, stream>>>(
        Qbf, Kbf, pfQ, pfK, Cc, ssum, ssq, bifp, pcp,
        w2h, w2l, xbf, w2b, vwh2, vwl2, sQ, sQ, 1, 1024);
  } else {
    chaotic_vwt<<<1024, blk, 0, stream>>>(
        Qbf, Kbf, pfQ, pfK, Cc, ssum, ssq, bifp, pcp,
        w2h, w2l, xbf, w2b, vwh, vwl, sQ, sQ, 0, 1024);
    chaotic_vwt<<<512, blk, 0, stream>>>(
        Qbf, Kbf, pfQ, pfK, Cc, ssum, ssq, bifp, pcp,
        w2h, w2l, xbf, w2b, vwh, vwl, sQ, sQ, 0, 0);
  }

  // ---- softmax (overlays Q/K) ----
  softmax_bf<<<dim3(S_LEN, N_BATCH), blk, 0, stream>>>(Cc, attn);
  // ---- out = attn @ (VWth+VWtl)^T + bo (T1+supertile) ----
  gemm_bsplit<<<512, blk, 0, stream>>>(
      attn, fused ? vwh2 : vwh, fused ? vwl2 : vwl, bo, out,
      D_MODEL, S_LEN, sS, sQ, sQ);
  // ---- sync_loss ----
  syncloss_kernel<<<1, 1024, 0, stream>>>(ssum, ssq, out + TD);
}

// Round 11
// 437.567 us; speedup vs baseline: 1.0622x; 1.0622x over previous
//
#include <hip/hip_runtime.h>
#include <hip/hip_bf16.h>
#include <math.h>

#define S_LEN 2048
#define D_MODEL 1024
#define N_BATCH 4
#define N_HALF 512

typedef unsigned short u16;
typedef __attribute__((ext_vector_type(8))) short bf16x8;
typedef __attribute__((ext_vector_type(4))) float f32x4;

// ---------- helpers ----------
__device__ inline u16 f2bf(float v) {
  __hip_bfloat16 h = __float2bfloat16(v);   // RNE
  return *reinterpret_cast<u16*>(&h);
}
__device__ inline float bf2f(u16 u) {
  __hip_bfloat16 h = *reinterpret_cast<__hip_bfloat16*>(&u);
  return __bfloat162float(h);
}
// async global->LDS, 16B per lane; LDS dest is wave-uniform base + lane*16
__device__ inline void gl2lds16(const void* g, void* l) {
  __builtin_amdgcn_global_load_lds(
      (const __attribute__((address_space(1))) unsigned int*)g,
      (__attribute__((address_space(3))) unsigned int*)l, 16, 0, 0);
}
// tanh via v_exp_f32; exact at 0, saturates correctly at +/-inf (no NaN)
__device__ inline float fast_tanh(float x) {
  float e = __expf(2.0f * x);
  return 1.0f - 2.0f / (e + 1.0f);
}
// XCD-chunked bijective swizzle (T1/m157): valid when n % 8 == 0.
__device__ inline int xcd_swz(int hw, int n) {
  return (hw & 7) * (n >> 3) + (hw >> 3);
}

// ============================================================
// ROUND-11: selective revert (r10 post-mortem).
//  KEEP: chaotic_vwt T1+4x4 supertiles (counters: FETCH 256->205 MB,
//        dur 138->135us) and out3 direct w2h/w2l split epilogue
//        (removes cast_split launch + 12 MB traffic).
//  REVERT: prep mega-fusion and qk/pf/bsplit supertiles (r10 total
//        regressed +20us; r9's linear-chunk T1 preserved DRAM write-
//        stream contiguity -> back to r9 decodes + separate prep).
// ============================================================

// ---------- casts ----------
// one launch for x, Wq, Wk, Wp (plain) + Wo (split). Sizes are pow2.
#define N0_X   (2097152LL)   // TD/4
#define NW_W   (262144LL)    // WSZ/4
__global__ __launch_bounds__(256)
void cast_bf4_multi(const float* __restrict__ sx, u16* __restrict__ dx,
                    const float* __restrict__ s1, u16* __restrict__ d1,
                    const float* __restrict__ s2, u16* __restrict__ d2,
                    const float* __restrict__ s3, u16* __restrict__ d3,
                    const float* __restrict__ s4, u16* __restrict__ d4h,
                    u16* __restrict__ d4l) {
  long long i = (long long)blockIdx.x * 256 + threadIdx.x;
  if (i < N0_X) {
    float4 v = ((const float4*)sx)[i];
    ushort4 o;
    o.x = f2bf(v.x); o.y = f2bf(v.y); o.z = f2bf(v.z); o.w = f2bf(v.w);
    ((ushort4*)dx)[i] = o;
    return;
  }
  long long k = i - N0_X;
  int w = (int)(k >> 18);              // k / NW_W
  long long off = k & (NW_W - 1);
  if (w < 3) {
    const float* s = (w == 0) ? s1 : (w == 1) ? s2 : s3;
    u16* d        = (w == 0) ? d1 : (w == 1) ? d2 : d3;
    float4 v = ((const float4*)s)[off];
    ushort4 o;
    o.x = f2bf(v.x); o.y = f2bf(v.y); o.z = f2bf(v.z); o.w = f2bf(v.w);
    ((ushort4*)d)[off] = o;
  } else {
    float4 v = ((const float4*)s4)[off];
    ushort4 oh, ol;
    float f;
    oh.x = f2bf(v.x); f = v.x - bf2f(oh.x); ol.x = f2bf(f);
    oh.y = f2bf(v.y); f = v.y - bf2f(oh.y); ol.y = f2bf(f);
    oh.z = f2bf(v.z); f = v.z - bf2f(oh.z); ol.z = f2bf(f);
    oh.w = f2bf(v.w); f = v.w - bf2f(oh.w); ol.w = f2bf(f);
    ((ushort4*)d4h)[off] = oh;
    ((ushort4*)d4l)[off] = ol;
  }
}
// transpose + split: dst[i][j] = split(src[j][i]), 1024x1024
__global__ __launch_bounds__(256)
void transpose_split(const float* __restrict__ src, u16* __restrict__ hi,
                     u16* __restrict__ lo) {
  __shared__ float t[32][33];
  const int bx = blockIdx.x * 32;   // i-base (src col, dst row)
  const int by = blockIdx.y * 32;   // j-base (src row, dst col)
  const int c = threadIdx.x & 31;
  const int r0 = (threadIdx.x >> 5) * 4;
#pragma unroll
  for (int r = 0; r < 4; r++)
    t[r0 + r][c] = src[(long long)(by + r0 + r) * D_MODEL + bx + c];
  __syncthreads();
#pragma unroll
  for (int r = 0; r < 4; r++) {
    float v = t[c][r0 + r];
    long long idx = (long long)(bx + r0 + r) * D_MODEL + by + c;
    u16 h = f2bf(v);
    hi[idx] = h;
    lo[idx] = f2bf(v - bf2f(h));
  }
}
// w2b[d] = sum_j Wo[d][j] * bv[j]   (one block per d)
__global__ __launch_bounds__(256)
void w2_bias(const float* __restrict__ Wo, const float* __restrict__ bv,
             float* __restrict__ w2b) {
  const int d = blockIdx.x;
  const int tid = threadIdx.x;
  float acc = 0.f;
  for (int j = tid; j < D_MODEL; j += 256)
    acc += Wo[(long long)d * D_MODEL + j] * bv[j];
#pragma unroll
  for (int m = 1; m < 64; m <<= 1) acc += __shfl_xor(acc, m);
  __shared__ float red[4];
  if ((tid & 63) == 0) red[tid >> 6] = acc;
  __syncthreads();
  if (tid == 0) w2b[d] = red[0] + red[1] + red[2] + red[3];
}

// ============================================================
// MERGED: qk_fused (512 blk, r9 linear T1) + out3 (blocks 0..63,
// epilogue writes w2h/w2l split directly). 64 KB shared LDS arena.
// ============================================================
__global__ __launch_bounds__(256, 2)
void qk_out3(const u16* __restrict__ X, const u16* __restrict__ Wq,
             const u16* __restrict__ Wk,
             const float* __restrict__ bq, const float* __restrict__ bk,
             u16* __restrict__ Qo, u16* __restrict__ Ko,
             const u16* __restrict__ Ah3, const u16* __restrict__ Al3,
             const u16* __restrict__ Bh3, const u16* __restrict__ Bl3,
             u16* __restrict__ w2h, u16* __restrict__ w2l) {
  __shared__ __align__(16) u16 smem[4 * 128 * 64];   // 64 KB
  const int id   = blockIdx.x;
  const int tid  = threadIdx.x;
  const int wave = tid >> 6;
  const int lane = tid & 63;
  const int quad = lane >> 4;
  const int tc   = lane & 15;
  const int wm = (wave & 1) * 64;
  const int wn = (wave >> 1) * 64;
  const int srow8 = lane >> 3;
  const int scol  = ((lane & 7) ^ srow8) * 8;
  const int srowb = wave * 32;
  const int wb = srowb * 64;
  const long long r8 = 8LL * D_MODEL;
  const int swzA = tc & 7;

  if (id < 64) {
    // ---------------- out3 body: split(W2) = (Ah+Al)(Bh+Bl)^T ----------
    u16* Ash = smem;
    u16* Asl = smem + 8192;
    u16* Bsh = smem + 16384;
    u16* Bsl = smem + 24576;
    const int bm = (id >> 3) * 128;
    const int bn = (id & 7) * 128;

    f32x4 acc[4][4];
#pragma unroll
    for (int i = 0; i < 4; i++)
#pragma unroll
      for (int j = 0; j < 4; j++) acc[i][j] = (f32x4){0.f, 0.f, 0.f, 0.f};

    long long aoff = (long long)(bm + srowb + srow8) * D_MODEL + scol;
    long long boff = (long long)(bn + srowb + srow8) * D_MODEL + scol;
    const u16 *gah = Ah3 + aoff, *gal = Al3 + aoff;
    const u16 *gbh = Bh3 + boff, *gbl = Bl3 + boff;

    for (int k0 = 0; k0 < D_MODEL; k0 += 64) {
#pragma unroll
      for (int c = 0; c < 4; c++) {
        gl2lds16(gah + c * r8, Ash + wb + c * 512);
        gl2lds16(gal + c * r8, Asl + wb + c * 512);
        gl2lds16(gbh + c * r8, Bsh + wb + c * 512);
        gl2lds16(gbl + c * r8, Bsl + wb + c * 512);
      }
      gah += 64; gal += 64; gbh += 64; gbl += 64;
      __syncthreads();
      bf16x8 ah[4][2], al[4][2], bh[4][2], bl[4][2];
#pragma unroll
      for (int i = 0; i < 4; i++) {
        const int ra = (wm + i * 16 + tc) * 64;
        const int rb = (wn + i * 16 + tc) * 64;
#pragma unroll
        for (int ks = 0; ks < 2; ks++) {
          const int co = ((ks * 4 + quad) ^ swzA) * 8;
          ah[i][ks] = *(const bf16x8*)(Ash + ra + co);
          al[i][ks] = *(const bf16x8*)(Asl + ra + co);
          bh[i][ks] = *(const bf16x8*)(Bsh + rb + co);
          bl[i][ks] = *(const bf16x8*)(Bsl + rb + co);
        }
      }
#pragma unroll
      for (int i = 0; i < 4; i++)
#pragma unroll
        for (int j = 0; j < 4; j++) {
#pragma unroll
          for (int ks = 0; ks < 2; ks++) {
            acc[i][j] = __builtin_amdgcn_mfma_f32_16x16x32_bf16(ah[i][ks], bh[j][ks], acc[i][j], 0, 0, 0);
            acc[i][j] = __builtin_amdgcn_mfma_f32_16x16x32_bf16(ah[i][ks], bl[j][ks], acc[i][j], 0, 0, 0);
            acc[i][j] = __builtin_amdgcn_mfma_f32_16x16x32_bf16(al[i][ks], bh[j][ks], acc[i][j], 0, 0, 0);
          }
        }
      __syncthreads();
    }
#pragma unroll
    for (int i = 0; i < 4; i++) {
      const int row0 = bm + wm + i * 16 + quad * 4;
#pragma unroll
      for (int j = 0; j < 4; j++) {
        const int col = bn + wn + j * 16 + tc;
#pragma unroll
        for (int r = 0; r < 4; r++) {
          long long idx = (long long)(row0 + r) * D_MODEL + col;
          float v = acc[i][j][r];
          u16 h = f2bf(v);
          w2h[idx] = h;
          w2l[idx] = f2bf(v - bf2f(h));
        }
      }
    }
  } else {
    // ------------- qk body: r9 linear T1 decode -------------
    u16* Xs = smem;
    u16* Qs = smem + 8192;
    u16* Ks = smem + 16384;
    const int qid = xcd_swz(id - 64, 512);
    const int bn = (qid & 7) * 128;
    const int bm = (qid >> 3) * 128;

    f32x4 acc1[4][4], acc2[4][4];
#pragma unroll
    for (int i = 0; i < 4; i++)
#pragma unroll
      for (int j = 0; j < 4; j++) {
        acc1[i][j] = (f32x4){0.f, 0.f, 0.f, 0.f};
        acc2[i][j] = (f32x4){0.f, 0.f, 0.f, 0.f};
      }

    const u16* gx = X  + (long long)(bm + srowb + srow8) * D_MODEL + scol;
    const u16* gq = Wq + (long long)(bn + srowb + srow8) * D_MODEL + scol;
    const u16* gk = Wk + (long long)(bn + srowb + srow8) * D_MODEL + scol;

    for (int k0 = 0; k0 < D_MODEL; k0 += 64) {
#pragma unroll
      for (int c = 0; c < 4; c++) {
        gl2lds16(gx + c * r8, Xs + wb + c * 512);
        gl2lds16(gq + c * r8, Qs + wb + c * 512);
        gl2lds16(gk + c * r8, Ks + wb + c * 512);
      }
      gx += 64; gq += 64; gk += 64;
      __syncthreads();
      bf16x8 af[4][2], bq4[4][2], bk4[4][2];
#pragma unroll
      for (int i = 0; i < 4; i++) {
        const int ra = (wm + i * 16 + tc) * 64;
        const int rb = (wn + i * 16 + tc) * 64;
#pragma unroll
        for (int ks = 0; ks < 2; ks++) {
          const int co = ((ks * 4 + quad) ^ swzA) * 8;
          af[i][ks]  = *(const bf16x8*)(Xs + ra + co);
          bq4[i][ks] = *(const bf16x8*)(Qs + rb + co);
          bk4[i][ks] = *(const bf16x8*)(Ks + rb + co);
        }
      }
#pragma unroll
      for (int i = 0; i < 4; i++)
#pragma unroll
        for (int j = 0; j < 4; j++) {
          acc1[i][j] = __builtin_amdgcn_mfma_f32_16x16x32_bf16(af[i][0], bq4[j][0], acc1[i][j], 0, 0, 0);
          acc2[i][j] = __builtin_amdgcn_mfma_f32_16x16x32_bf16(af[i][0], bk4[j][0], acc2[i][j], 0, 0, 0);
          acc1[i][j] = __builtin_amdgcn_mfma_f32_16x16x32_bf16(af[i][1], bq4[j][1], acc1[i][j], 0, 0, 0);
          acc2[i][j] = __builtin_amdgcn_mfma_f32_16x16x32_bf16(af[i][1], bk4[j][1], acc2[i][j], 0, 0, 0);
        }
      __syncthreads();
    }

#pragma unroll
    for (int i = 0; i < 4; i++) {
      const int row0 = bm + wm + i * 16 + quad * 4;
#pragma unroll
      for (int j = 0; j < 4; j++) {
        const int col = bn + wn + j * 16 + tc;
#pragma unroll
        for (int r = 0; r < 4; r++) {
          long long idx = (long long)(row0 + r) * D_MODEL + col;
          Qo[idx] = f2bf(acc1[i][j][r] + bq[col]);
          Ko[idx] = f2bf(acc2[i][j][r] + bk[col]);
        }
      }
    }
  }
}

// ============================================================
// Fused pfQ+pfK projection + in-kernel phase normalize.
// r9 linear T1 decode.
// ============================================================
__global__ __launch_bounds__(256, 2)
void pf_fused(const u16* __restrict__ Qb, const u16* __restrict__ Wp,
              const float* __restrict__ bp,
              u16* __restrict__ pfQ, u16* __restrict__ pfK,
              long long TDo) {
  __shared__ u16 lds_all[3 * 128 * 64];   // Qs | Ks | Ws (48 KB)
  u16* Qs = lds_all;
  u16* Ks = lds_all + 128 * 64;
  u16* Ws = lds_all + 2 * 128 * 64;
  const int tid  = threadIdx.x;
  const int wave = tid >> 6;
  const int lane = tid & 63;
  const int quad = lane >> 4;
  const int tc   = lane & 15;
  const int oid = xcd_swz(blockIdx.x, 512);
  const int bm = (oid >> 3) * 128;
  const int bn = (oid & 7) * 64;           // re-col base (im = +512)
  const int wm = (wave & 1) * 64;
  const int grp = wave >> 1;               // 0: re-group, 1: im-group

  f32x4 acc1[4][4], acc2[4][4];
#pragma unroll
  for (int i = 0; i < 4; i++)
#pragma unroll
    for (int j = 0; j < 4; j++) {
      acc1[i][j] = (f32x4){0.f, 0.f, 0.f, 0.f};
      acc2[i][j] = (f32x4){0.f, 0.f, 0.f, 0.f};
    }

  const int srow8 = lane >> 3;
  const int scol  = ((lane & 7) ^ srow8) * 8;
  const int srowb = wave * 32;
  const u16* gq = Qb + (long long)(bm + srowb + srow8) * D_MODEL + scol;
  const u16* gk = gq + TDo;
  const u16* gw = Wp + (long long)(bn + srowb + srow8 + ((wave & 2) ? 448 : 0)) * D_MODEL + scol;
  const int wb = srowb * 64;
  const long long r8 = 8LL * D_MODEL;
  const int swzA = tc & 7;

  for (int k0 = 0; k0 < D_MODEL; k0 += 64) {
#pragma unroll
    for (int c = 0; c < 4; c++) {
      gl2lds16(gq + c * r8, Qs + wb + c * 512);
      gl2lds16(gk + c * r8, Ks + wb + c * 512);
      gl2lds16(gw + c * r8, Ws + wb + c * 512);
    }
    gq += 64; gk += 64; gw += 64;
    __syncthreads();
    bf16x8 aq[4][2], ak[4][2], bw[4][2];
    const int wn = grp * 64;
#pragma unroll
    for (int i = 0; i < 4; i++) {
      const int ra = (wm + i * 16 + tc) * 64;
      const int rb = (wn + i * 16 + tc) * 64;
#pragma unroll
      for (int ks = 0; ks < 2; ks++) {
        const int co = ((ks * 4 + quad) ^ swzA) * 8;
        aq[i][ks] = *(const bf16x8*)(Qs + ra + co);
        ak[i][ks] = *(const bf16x8*)(Ks + ra + co);
        bw[i][ks] = *(const bf16x8*)(Ws + rb + co);
      }
    }
#pragma unroll
    for (int i = 0; i < 4; i++)
#pragma unroll
      for (int j = 0; j < 4; j++) {
        acc1[i][j] = __builtin_amdgcn_mfma_f32_16x16x32_bf16(aq[i][0], bw[j][0], acc1[i][j], 0, 0, 0);
        acc2[i][j] = __builtin_amdgcn_mfma_f32_16x16x32_bf16(ak[i][0], bw[j][0], acc2[i][j], 0, 0, 0);
        acc1[i][j] = __builtin_amdgcn_mfma_f32_16x16x32_bf16(aq[i][1], bw[j][1], acc1[i][j], 0, 0, 0);
        acc2[i][j] = __builtin_amdgcn_mfma_f32_16x16x32_bf16(ak[i][1], bw[j][1], acc2[i][j], 0, 0, 0);
      }
    __syncthreads();
  }

  // ---- fused phase-normalize epilogue (exchange via LDS, 4 rounds) ----
  float* ex = (float*)lds_all;             // 32 KB of the 48 KB staging
  const long long colbase = (long long)bn + (long long)grp * 512;
#pragma unroll
  for (int o = 0; o < 2; o++) {
    u16* Ou = o ? pfK : pfQ;
#pragma unroll
    for (int half = 0; half < 2; half++) {
      int cnt = 0;
#pragma unroll
      for (int i = 2 * half; i < 2 * half + 2; i++)
#pragma unroll
        for (int j = 0; j < 4; j++) {
          f32x4 v = o ? acc2[i][j] : acc1[i][j];
          float b = bp[colbase + j * 16 + tc];
          v[0] += b; v[1] += b; v[2] += b; v[3] += b;
          *(f32x4*)(ex + wave * 2048 + cnt * 256 + lane * 4) = v;
          cnt++;
        }
      __syncthreads();
      cnt = 0;
#pragma unroll
      for (int i = 2 * half; i < 2 * half + 2; i++)
#pragma unroll
        for (int j = 0; j < 4; j++) {
          f32x4 own = *(const f32x4*)(ex + wave * 2048 + cnt * 256 + lane * 4);
          f32x4 oth = *(const f32x4*)(ex + (wave ^ 2) * 2048 + cnt * 256 + lane * 4);
          const int row0 = bm + wm + i * 16 + quad * 4;
          const long long col = colbase + j * 16 + tc;
#pragma unroll
          for (int r = 0; r < 4; r++) {
            float a = own[r], p = oth[r];
            float n2 = a * a + p * p;
            float outv = (grp == 0) ? 1.f : 0.f;
            if (n2 > 0.f) outv = a * (1.0f / sqrtf(n2));
            Ou[(long long)(row0 + r) * D_MODEL + col] = f2bf(outv);
          }
          cnt++;
        }
      __syncthreads();
    }
  }
}

// ============================================================
// MERGED: chaotic_fused + vwt_kernel, interleaved 2:1, T1 + supertiles
// (round-10 decodes — validated: FETCH 256->205 MB, dur 138->135us).
// ============================================================
__global__ __launch_bounds__(256, 2)
void chaotic_vwt(const u16* __restrict__ Q, const u16* __restrict__ Kt,
                 const u16* __restrict__ Uq, const u16* __restrict__ Uk,
                 float* __restrict__ Cc,
                 float* __restrict__ ssum, float* __restrict__ ssq,
                 const float* __restrict__ bifp, const float* __restrict__ pcp,
                 const u16* __restrict__ W2h, const u16* __restrict__ W2l,
                 const u16* __restrict__ X, const float* __restrict__ w2b,
                 u16* __restrict__ Ch, u16* __restrict__ Cl,
                 long long sB, long long sC,
                 int interleave, int nchao) {
  __shared__ __align__(16) u16 smem[4 * 128 * 64];   // 64 KB
  const int id = xcd_swz(blockIdx.x, (int)gridDim.x);   // T1 (grid % 8 == 0)
  int cid = -1, vid = -1;
  if (interleave) {
    if ((id % 3) == 2) vid = id / 3;
    else cid = (id / 3) * 2 + (id % 3);
  } else {
    if (id < nchao) cid = id; else vid = id - nchao;
  }

  const int tid  = threadIdx.x;
  const int wave = tid >> 6;
  const int lane = tid & 63;
  const int quad = lane >> 4;
  const int tc   = lane & 15;
  const int wm = (wave & 1) * 64;
  const int wn = (wave >> 1) * 64;
  const int srow8 = lane >> 3;
  const int scol  = ((lane & 7) ^ srow8) * 8;
  const int srowb = wave * 32;
  const int wb = srowb * 64;
  const long long r8 = 8LL * D_MODEL;
  const int swzA = tc & 7;

  if (cid >= 0) {
    // ---------------- chaotic body (4x4 supertile decode) ----------------
    u16* Qs = smem;
    u16* Ks = smem + 8192;
    u16* Us = smem + 16384;
    u16* Ws = smem + 24576;
    const int chunk = cid >> 7;
    const int t = cid & 127;
    const int st = t >> 4, sp = t & 15;
    const int bn = (((st & 3) << 2) + (sp & 3)) * 128;
    const int bm = (((chunk & 1) << 3) + ((st >> 2) << 2) + (sp >> 2)) * 128;
    const long long z = chunk >> 1;
    const long long sQ = (long long)S_LEN * D_MODEL;

    f32x4 acc1[4][4], acc2[4][4];
#pragma unroll
    for (int i = 0; i < 4; i++)
#pragma unroll
      for (int j = 0; j < 4; j++) {
        acc1[i][j] = (f32x4){0.f, 0.f, 0.f, 0.f};
        acc2[i][j] = (f32x4){0.f, 0.f, 0.f, 0.f};
      }

    const u16* gq = Q  + z * sQ + (long long)(bm + srowb + srow8) * D_MODEL + scol;
    const u16* gk = Kt + z * sQ + (long long)(bn + srowb + srow8) * D_MODEL + scol;
    const u16* gu = Uq + z * sQ + (long long)(bm + srowb + srow8) * D_MODEL + scol;
    const u16* gw = Uk + z * sQ + (long long)(bn + srowb + srow8) * D_MODEL + scol;

    for (int k0 = 0; k0 < D_MODEL; k0 += 64) {
#pragma unroll
      for (int c = 0; c < 4; c++) {
        gl2lds16(gq + c * r8, Qs + wb + c * 512);
        gl2lds16(gk + c * r8, Ks + wb + c * 512);
        gl2lds16(gu + c * r8, Us + wb + c * 512);
        gl2lds16(gw + c * r8, Ws + wb + c * 512);
      }
      gq += 64; gk += 64; gu += 64; gw += 64;
      __syncthreads();
      {   // GEMM 1: scores = Q @ K^T
        bf16x8 af[4][2], bg[4][2];
#pragma unroll
        for (int i = 0; i < 4; i++) {
          const int ra = (wm + i * 16 + tc) * 64;
          const int rb = (wn + i * 16 + tc) * 64;
#pragma unroll
          for (int ks = 0; ks < 2; ks++) {
            const int co = ((ks * 4 + quad) ^ swzA) * 8;
            af[i][ks] = *(const bf16x8*)(Qs + ra + co);
            bg[i][ks] = *(const bf16x8*)(Ks + rb + co);
          }
        }
#pragma unroll
        for (int i = 0; i < 4; i++)
#pragma unroll
          for (int j = 0; j < 4; j++) {
            acc1[i][j] = __builtin_amdgcn_mfma_f32_16x16x32_bf16(af[i][0], bg[j][0], acc1[i][j], 0, 0, 0);
            acc1[i][j] = __builtin_amdgcn_mfma_f32_16x16x32_bf16(af[i][1], bg[j][1], acc1[i][j], 0, 0, 0);
          }
      }
      {   // GEMM 2: sync = Uq @ Uk^T
        bf16x8 cf[4][2], dg[4][2];
#pragma unroll
        for (int i = 0; i < 4; i++) {
          const int ra = (wm + i * 16 + tc) * 64;
          const int rb = (wn + i * 16 + tc) * 64;
#pragma unroll
          for (int ks = 0; ks < 2; ks++) {
            const int co = ((ks * 4 + quad) ^ swzA) * 8;
            cf[i][ks] = *(const bf16x8*)(Us + ra + co);
            dg[i][ks] = *(const bf16x8*)(Ws + rb + co);
          }
        }
#pragma unroll
        for (int i = 0; i < 4; i++)
#pragma unroll
          for (int j = 0; j < 4; j++) {
            acc2[i][j] = __builtin_amdgcn_mfma_f32_16x16x32_bf16(cf[i][0], dg[j][0], acc2[i][j], 0, 0, 0);
            acc2[i][j] = __builtin_amdgcn_mfma_f32_16x16x32_bf16(cf[i][1], dg[j][1], acc2[i][j], 0, 0, 0);
          }
      }
      __syncthreads();
    }

    const float bif = *bifp;
    const float pc  = *pcp;
    float rsum[4][4], rsq[4][4];
#pragma unroll
    for (int i = 0; i < 4; i++)
#pragma unroll
      for (int r = 0; r < 4; r++) { rsum[i][r] = 0.f; rsq[i][r] = 0.f; }

    float* C = Cc + z * (long long)S_LEN * S_LEN;
#pragma unroll
    for (int i = 0; i < 4; i++) {
      const int row0 = bm + wm + i * 16 + quad * 4;
#pragma unroll
      for (int j = 0; j < 4; j++) {
        const int col = bn + wn + j * 16 + tc;
#pragma unroll
        for (int r = 0; r < 4; r++) {
          float sc = acc1[i][j][r] * 0.03125f;          // / sqrt(1024)
          float sy = acc2[i][j][r] * (1.0f / 512.0f);   // / HALF
          float t2 = fast_tanh(sc);
          C[(long long)(row0 + r) * S_LEN + col] = sc + pc * sy + bif * t2 * (1.0f - t2);
          rsum[i][r] += sy;
          rsq[i][r]  += sy * sy;
        }
      }
    }
#pragma unroll
    for (int m = 1; m < 16; m <<= 1) {
#pragma unroll
      for (int i = 0; i < 4; i++)
#pragma unroll
        for (int r = 0; r < 4; r++) {
          rsum[i][r] += __shfl_xor(rsum[i][r], m);
          rsq[i][r]  += __shfl_xor(rsq[i][r], m);
        }
    }
    if (tc == 0) {
#pragma unroll
      for (int i = 0; i < 4; i++)
#pragma unroll
        for (int r = 0; r < 4; r++) {
          long long rr = z * S_LEN + bm + wm + i * 16 + quad * 4 + r;
          atomicAdd(&ssum[rr], rsum[i][r]);
          atomicAdd(&ssq[rr],  rsq[i][r]);
        }
    }
  } else {
    // ---------------- vwt body (4x4 supertile decode) ----------------
    u16* Ah = smem;
    u16* Al = smem + 8192;
    u16* Bs = smem + 16384;
    const int chunk = vid >> 6;
    const int t = vid & 63;
    const int bn = (((t >> 4) << 2) + (t & 3)) * 128;          // s
    const int bm = (((chunk & 1) << 2) + ((t >> 2) & 3)) * 128; // d
    const long long z = chunk >> 1;

    f32x4 acc[4][4];
#pragma unroll
    for (int i = 0; i < 4; i++)
#pragma unroll
      for (int j = 0; j < 4; j++) acc[i][j] = (f32x4){0.f, 0.f, 0.f, 0.f};

    const long long aoff = (long long)(bm + srowb + srow8) * D_MODEL + scol;
    const u16* gah = W2h + aoff;
    const u16* gal = W2l + aoff;
    const u16* gb  = X + z * sB + (long long)(bn + srowb + srow8) * D_MODEL + scol;

    for (int k0 = 0; k0 < D_MODEL; k0 += 64) {
#pragma unroll
      for (int c = 0; c < 4; c++) {
        gl2lds16(gah + c * r8, Ah + wb + c * 512);
        gl2lds16(gal + c * r8, Al + wb + c * 512);
        gl2lds16(gb  + c * r8, Bs + wb + c * 512);
      }
      gah += 64; gal += 64; gb += 64;
      __syncthreads();
      bf16x8 ah4[4][2], al4[4][2], bx[4][2];
#pragma unroll
      for (int i = 0; i < 4; i++) {
        const int ra = (wm + i * 16 + tc) * 64;
        const int rb = (wn + i * 16 + tc) * 64;
#pragma unroll
        for (int ks = 0; ks < 2; ks++) {
          const int co = ((ks * 4 + quad) ^ swzA) * 8;
          ah4[i][ks] = *(const bf16x8*)(Ah + ra + co);
          al4[i][ks] = *(const bf16x8*)(Al + ra + co);
          bx[i][ks]  = *(const bf16x8*)(Bs + rb + co);
        }
      }
#pragma unroll
      for (int i = 0; i < 4; i++)
#pragma unroll
        for (int j = 0; j < 4; j++) {
          acc[i][j] = __builtin_amdgcn_mfma_f32_16x16x32_bf16(ah4[i][0], bx[j][0], acc[i][j], 0, 0, 0);
          acc[i][j] = __builtin_amdgcn_mfma_f32_16x16x32_bf16(al4[i][0], bx[j][0], acc[i][j], 0, 0, 0);
          acc[i][j] = __builtin_amdgcn_mfma_f32_16x16x32_bf16(ah4[i][1], bx[j][1], acc[i][j], 0, 0, 0);
          acc[i][j] = __builtin_amdgcn_mfma_f32_16x16x32_bf16(al4[i][1], bx[j][1], acc[i][j], 0, 0, 0);
        }
      __syncthreads();
    }

    u16* Chz = Ch + z * sC;
    u16* Clz = Cl + z * sC;
#pragma unroll
    for (int i = 0; i < 4; i++) {
      const int row0 = bm + wm + i * 16 + quad * 4;
#pragma unroll
      for (int j = 0; j < 4; j++) {
        const int col = bn + wn + j * 16 + tc;
#pragma unroll
        for (int r = 0; r < 4; r++) {
          float v = acc[i][j][r] + w2b[row0 + r];
          long long idx = (long long)(row0 + r) * S_LEN + col;
          u16 h = f2bf(v);
          Chz[idx] = h;
          Clz[idx] = f2bf(v - bf2f(h));
        }
      }
    }
  }
}

// ============================================================
// B-split GEMM (out): C = A @ (Bh+Bl)^T + bias[col], fp32 out.
// r9 linear T1 decode.
// ============================================================
__global__ __launch_bounds__(256)
void gemm_bsplit(const u16* __restrict__ A,
                 const u16* __restrict__ Bh, const u16* __restrict__ Bl,
                 const float* __restrict__ bias, float* __restrict__ C,
                 int N, int K, long long sA, long long sB, long long sC) {
  __shared__ u16 As[128 * 64];
  __shared__ u16 Bsh[128 * 64];
  __shared__ u16 Bsl[128 * 64];
  const int tid  = threadIdx.x;
  const int wave = tid >> 6;
  const int lane = tid & 63;
  const int quad = lane >> 4;
  const int tc   = lane & 15;
  const int oid = xcd_swz(blockIdx.x, (int)gridDim.x);   // T1
  const int bn = (oid & 7) * 128;
  const int bm = ((oid >> 3) & 15) * 128;
  const long long z = oid >> 7;
  const int wm = (wave & 1) * 64;
  const int wn = (wave >> 1) * 64;

  f32x4 acc[4][4];
#pragma unroll
  for (int i = 0; i < 4; i++)
#pragma unroll
    for (int j = 0; j < 4; j++) acc[i][j] = (f32x4){0.f, 0.f, 0.f, 0.f};

  const int srow8 = lane >> 3;
  const int scol  = ((lane & 7) ^ srow8) * 8;
  const int srowb = wave * 32;
  const long long boff = (long long)(bn + srowb + srow8) * K + scol;
  const u16* ga  = A + z * sA + (long long)(bm + srowb + srow8) * K + scol;
  const u16* gbh = Bh + z * sB + boff;
  const u16* gbl = Bl + z * sB + boff;
  const int wb = srowb * 64;
  const long long r8K = 8LL * K;
  const int swzA = tc & 7;

  for (int k0 = 0; k0 < K; k0 += 64) {
#pragma unroll
    for (int c = 0; c < 4; c++) {
      gl2lds16(ga  + c * r8K, As  + wb + c * 512);
      gl2lds16(gbh + c * r8K, Bsh + wb + c * 512);
      gl2lds16(gbl + c * r8K, Bsl + wb + c * 512);
    }
    ga += 64; gbh += 64; gbl += 64;
    __syncthreads();
    bf16x8 af[4][2], bh[4][2], bl[4][2];
#pragma unroll
    for (int i = 0; i < 4; i++) {
      const int ra = (wm + i * 16 + tc) * 64;
      const int rb = (wn + i * 16 + tc) * 64;
#pragma unroll
      for (int ks = 0; ks < 2; ks++) {
        const int co = ((ks * 4 + quad) ^ swzA) * 8;
        af[i][ks] = *(const bf16x8*)(As  + ra + co);
        bh[i][ks] = *(const bf16x8*)(Bsh + rb + co);
        bl[i][ks] = *(const bf16x8*)(Bsl + rb + co);
      }
    }
#pragma unroll
    for (int i = 0; i < 4; i++)
#pragma unroll
      for (int j = 0; j < 4; j++) {
        acc[i][j] = __builtin_amdgcn_mfma_f32_16x16x32_bf16(af[i][0], bh[j][0], acc[i][j], 0, 0, 0);
        acc[i][j] = __builtin_amdgcn_mfma_f32_16x16x32_bf16(af[i][0], bl[j][0], acc[i][j], 0, 0, 0);
        acc[i][j] = __builtin_amdgcn_mfma_f32_16x16x32_bf16(af[i][1], bh[j][1], acc[i][j], 0, 0, 0);
        acc[i][j] = __builtin_amdgcn_mfma_f32_16x16x32_bf16(af[i][1], bl[j][1], acc[i][j], 0, 0, 0);
      }
    __syncthreads();
  }

  float* Cz = C + z * sC;
#pragma unroll
  for (int i = 0; i < 4; i++) {
    const int row0 = bm + wm + i * 16 + quad * 4;
#pragma unroll
    for (int j = 0; j < 4; j++) {
      const int col = bn + wn + j * 16 + tc;
#pragma unroll
      for (int r = 0; r < 4; r++)
        Cz[(long long)(row0 + r) * N + col] = acc[i][j][r] + bias[col];
    }
  }
}

// ============================================================
// Row softmax: fp32 in (chaotic), bf16 out (attn). 1 block / row.
// Vectorized: 2x float4 loads + 2x ushort4 stores per lane.
// ============================================================
__global__ __launch_bounds__(256)
void softmax_bf(const float* __restrict__ Cc, u16* __restrict__ P) {
  const long long row = (long long)blockIdx.y * S_LEN + blockIdx.x;
  const int tid = threadIdx.x;
  const float* p = Cc + row * S_LEN + tid * 8;
  u16* q = P + row * S_LEN + tid * 8;
  float4 a = *(const float4*)p;
  float4 b = *(const float4*)(p + 4);
  float v[8] = {a.x, a.y, a.z, a.w, b.x, b.y, b.z, b.w};
  float m = v[0];
#pragma unroll
  for (int i = 1; i < 8; i++) m = fmaxf(m, v[i]);
#pragma unroll
  for (int mask = 1; mask < 64; mask <<= 1) m = fmaxf(m, __shfl_xor(m, mask));
  __shared__ float red[8];
  if ((tid & 63) == 0) red[tid >> 6] = m;
  __syncthreads();
  m = fmaxf(fmaxf(red[0], red[1]), fmaxf(red[2], red[3]));
  float s = 0.f;
#pragma unroll
  for (int i = 0; i < 8; i++) { v[i] = __expf(v[i] - m); s += v[i]; }
#pragma unroll
  for (int mask = 1; mask < 64; mask <<= 1) s += __shfl_xor(s, mask);
  __syncthreads();
  if ((tid & 63) == 0) red[4 + (tid >> 6)] = s;
  __syncthreads();
  s = red[4] + red[5] + red[6] + red[7];
  float inv = 1.0f / s;
  ushort4 o0, o1;
  o0.x = f2bf(v[0] * inv); o0.y = f2bf(v[1] * inv);
  o0.z = f2bf(v[2] * inv); o0.w = f2bf(v[3] * inv);
  o1.x = f2bf(v[4] * inv); o1.y = f2bf(v[5] * inv);
  o1.z = f2bf(v[6] * inv); o1.w = f2bf(v[7] * inv);
  *(ushort4*)q = o0;
  *(ushort4*)(q + 4) = o1;
}

// ============================================================
// sync_loss
// ============================================================
__global__ __launch_bounds__(1024)
void syncloss_kernel(const float* __restrict__ ssum, const float* __restrict__ ssq,
                     float* __restrict__ out) {
  const int tid = threadIdx.x;
  float acc = 0.f;
  for (int r = tid; r < N_BATCH * S_LEN; r += 1024) {
    float su = ssum[r], sq = ssq[r];
    acc += (sq - su * su * (1.0f / 2048.0f)) * (1.0f / 2047.0f);
  }
#pragma unroll
  for (int mask = 1; mask < 64; mask <<= 1) acc += __shfl_xor(acc, mask);
  __shared__ float red[16];
  if ((tid & 63) == 0) red[tid >> 6] = acc;
  __syncthreads();
  if (tid == 0) {
    float t = 0.f;
#pragma unroll
    for (int k = 0; k < 16; k++) t += red[k];
    out[0] = 0.01f * (t / (float)(N_BATCH * S_LEN));
  }
}

extern "C" void kernel_launch(void* const* d_in, const int* in_sizes, int n_in,
                              void* d_out, int out_size, void* d_ws, size_t ws_size,
                              hipStream_t stream) {
  const float* x    = (const float*)d_in[0];
  const float* Wq   = (const float*)d_in[1];
  const float* bq   = (const float*)d_in[2];
  const float* Wk   = (const float*)d_in[3];
  const float* bk   = (const float*)d_in[4];
  const float* Wv   = (const float*)d_in[5];
  const float* bv   = (const float*)d_in[6];
  const float* Wp   = (const float*)d_in[7];
  const float* bp   = (const float*)d_in[8];
  const float* Wo   = (const float*)d_in[9];
  const float* bo   = (const float*)d_in[10];
  const float* bifp = (const float*)d_in[11];
  const float* pcp  = (const float*)d_in[12];
  float* out = (float*)d_out;

  const long long NROW = (long long)N_BATCH * S_LEN;   // 8192
  const long long TD   = NROW * D_MODEL;               // 8,388,608
  const long long WSZ  = (long long)D_MODEL * D_MODEL; // 1,048,576

  // workspace layout (W2f slot unused, kept for layout stability)
  u16* xbf   = (u16*)d_ws;          // TD
  u16* wqb   = xbf + TD;            // WSZ
  u16* wkb   = wqb + WSZ;           // WSZ
  u16* wpb   = wkb + WSZ;           // WSZ
  u16* woh   = wpb + WSZ;           // WSZ (Wo hi/lo)
  u16* wol   = woh + WSZ;
  u16* wvth  = wol + WSZ;           // WSZ (Wv^T hi/lo)
  u16* wvtl  = wvth + WSZ;
  u16* w2h   = wvtl + WSZ;          // WSZ (W2 hi/lo)
  u16* w2l   = w2h + WSZ;
  float* W2f = (float*)(w2l + WSZ); // WSZ floats (unused)
  float* w2b = W2f + WSZ;           // 1024 floats
  u16* Qbf   = (u16*)(w2b + D_MODEL); // TD
  u16* Kbf   = Qbf + TD;            // TD (contiguous)
  u16* pfQ   = Kbf + TD;            // TD
  u16* pfK   = pfQ + TD;            // TD (contiguous)
  float* Cc  = (float*)(pfK + TD);  // B*S*S fp32 (67 MB)
  float* ssum = Cc + (long long)N_BATCH * S_LEN * S_LEN;
  float* ssq  = ssum + NROW;
  u16* attn = Qbf;                  // overlays Q+K after chaotic (2*TD)
  u16* vwh  = pfQ;                  // fallback overlay (Uq dead after chaotic)
  u16* vwl  = pfK;
  // fresh vwt buffers for the fused path
  u16* vwh2 = (u16*)(ssq + NROW);
  u16* vwl2 = vwh2 + TD;
  const size_t need = (size_t)((char*)(vwl2 + TD) - (char*)d_ws);
  const bool fused = (ws_size >= need);

  dim3 blk(256);
  const long long sQ = (long long)S_LEN * D_MODEL;   // 2048*1024
  const long long sS = (long long)S_LEN * S_LEN;

  // ---- casts (x, Wq, Wk, Wp plain + Wo split in ONE launch) ----
  cast_bf4_multi<<<12288, blk, 0, stream>>>(x, xbf, Wq, wqb, Wk, wkb, Wp, wpb,
                                            Wo, woh, wol);
  transpose_split<<<dim3(32, 32), blk, 0, stream>>>(Wv, wvth, wvtl);
  // ---- merged: Q,K projection (T1) + W2 GEMM -> split directly ----
  qk_out3<<<576, blk, 0, stream>>>(xbf, wqb, wkb, bq, bk, Qbf, Kbf,
                                   woh, wol, wvth, wvtl, w2h, w2l);
  w2_bias<<<D_MODEL, blk, 0, stream>>>(Wo, bv, w2b);

  // ---- pfQ,pfK fused projection + phase normalize (T1) ----
  pf_fused<<<512, blk, 0, stream>>>(Qbf, wpb, bp, pfQ, pfK, TD);
  hipMemsetAsync(ssum, 0, (size_t)(2 * NROW) * sizeof(float), stream);

  // ---- merged chaotic + vwt (2:1, T1+supertile) or sequential fallback ----
  if (fused) {
    chaotic_vwt<<<1536, blk, 0, stream>>>(
        Qbf, Kbf, pfQ, pfK, Cc, ssum, ssq, bifp, pcp,
        w2h, w2l, xbf, w2b, vwh2, vwl2, sQ, sQ, 1, 1024);
  } else {
    chaotic_vwt<<<1024, blk, 0, stream>>>(
        Qbf, Kbf, pfQ, pfK, Cc, ssum, ssq, bifp, pcp,
        w2h, w2l, xbf, w2b, vwh, vwl, sQ, sQ, 0, 1024);
    chaotic_vwt<<<512, blk, 0, stream>>>(
        Qbf, Kbf, pfQ, pfK, Cc, ssum, ssq, bifp, pcp,
        w2h, w2l, xbf, w2b, vwh, vwl, sQ, sQ, 0, 0);
  }

  // ---- softmax (overlays Q/K) ----
  softmax_bf<<<dim3(S_LEN, N_BATCH), blk, 0, stream>>>(Cc, attn);
  // ---- out = attn @ (VWth+VWtl)^T + bo (T1) ----
  gemm_bsplit<<<512, blk, 0, stream>>>(
      attn, fused ? vwh2 : vwh, fused ? vwl2 : vwl, bo, out,
      D_MODEL, S_LEN, sS, sQ, sQ);
  // ---- sync_loss ----
  syncloss_kernel<<<1, 1024, 0, stream>>>(ssum, ssq, out + TD);
}